// Round 1
// baseline (2322.167 us; speedup 1.0000x reference)
//
#include <hip/hip_runtime.h>
#include <hip/hip_bf16.h>

#define NB 16384
#define NZ 128
#define NH 512
#define NHID 512
#define NT 32

typedef __attribute__((ext_vector_type(8))) short short8;
typedef __attribute__((ext_vector_type(4))) short short4v;
typedef __attribute__((ext_vector_type(4))) float f32x4;

__device__ __forceinline__ short f2bf(float x) {
    union { __hip_bfloat16 h; short s; } u; u.h = __float2bfloat16(x); return u.s;
}
__device__ __forceinline__ float bf2f(short s) {
    union { unsigned int u; float f; } v; v.u = ((unsigned int)(unsigned short)s) << 16; return v.f;
}

// ---------------------------------------------------------------------------
// Prologue: pack W1a^T, W2^T, W1b^T into MFMA A-fragment order (bf16).
// A-frag for 16x16x32: lane l holds A[m=l&15][k=(l>>4)*8+j], j=0..7 (16B/lane).
// w1aT order [ht(32)][kt(4)]; w2T order [kt(16)][jt(8)]; w1bT order [ht(32)][kt(16)]
// ---------------------------------------------------------------------------
__global__ __launch_bounds__(64) void pack_weights(const float* __restrict__ W1,
                                                   const float* __restrict__ W2,
                                                   short* __restrict__ w1aT,
                                                   short* __restrict__ w2T,
                                                   short* __restrict__ w1bT) {
    int f = blockIdx.x;
    int l = threadIdx.x;
    int quad = l >> 4, m = l & 15;
    float v[8];
    short* dst;
    if (f < 128) {                       // W1a^T : A[h][k] = W1[k][h], k<128
        int ht = f >> 2, kt = f & 3;
#pragma unroll
        for (int j = 0; j < 8; ++j)
            v[j] = W1[(size_t)(kt * 32 + quad * 8 + j) * NH + ht * 16 + m];
        dst = w1aT + ((size_t)f * 64 + l) * 8;
    } else if (f < 256) {                // W2^T : A[j][h] = W2[h][j]
        int g = f - 128; int kt = g >> 3, jt = g & 7;
#pragma unroll
        for (int j = 0; j < 8; ++j)
            v[j] = W2[(size_t)(kt * 32 + quad * 8 + j) * NZ + jt * 16 + m];
        dst = w2T + ((size_t)g * 64 + l) * 8;
    } else {                             // W1b^T : A[h][k] = W1[128+k][h]
        int g = f - 256; int ht = g >> 4, kt = g & 15;
#pragma unroll
        for (int j = 0; j < 8; ++j)
            v[j] = W1[(size_t)(128 + kt * 32 + quad * 8 + j) * NH + ht * 16 + m];
        dst = w1bT + ((size_t)g * 64 + l) * 8;
    }
    short8 o;
#pragma unroll
    for (int j = 0; j < 8; ++j) o[j] = f2bf(v[j]);
    *(short8*)dst = o;
}

// ---------------------------------------------------------------------------
// ctx_proj[b][h] = ctx[b]@W1b + b1, stored bf16. One wave = 16 rows.
// Computed as ctxp^T = W1b^T @ ctx^T so ctx regs double as B-frags.
// ---------------------------------------------------------------------------
__global__ __launch_bounds__(256) void ctxproj_kernel(const float* __restrict__ ctx,
                                                      const float* __restrict__ b1,
                                                      const short* __restrict__ w1bT,
                                                      short* __restrict__ ctxp) {
    int wave = (blockIdx.x << 2) + (threadIdx.x >> 6);
    int lane = threadIdx.x & 63;
    int quad = lane >> 4, m = lane & 15;
    int row = wave * 16 + m;

    short8 cb[16];
    const float* crow = ctx + (size_t)row * NH;
#pragma unroll
    for (int kt = 0; kt < 16; ++kt) {
        f32x4 a = *(const f32x4*)(crow + kt * 32 + quad * 8);
        f32x4 b = *(const f32x4*)(crow + kt * 32 + quad * 8 + 4);
        short8 t;
#pragma unroll
        for (int j = 0; j < 4; ++j) { t[j] = f2bf(a[j]); t[4 + j] = f2bf(b[j]); }
        cb[kt] = t;
    }
    const f32x4 zero = {0.f, 0.f, 0.f, 0.f};
    for (int c = 0; c < 4; ++c) {
        f32x4 acc[8];
#pragma unroll
        for (int i = 0; i < 8; ++i) acc[i] = zero;
        for (int kt = 0; kt < 16; ++kt) {
#pragma unroll
            for (int h8 = 0; h8 < 8; ++h8) {
                int ht = c * 8 + h8;
                short8 afr = *(const short8*)(w1bT + ((size_t)(ht * 16 + kt) * 64 + lane) * 8);
                acc[h8] = __builtin_amdgcn_mfma_f32_16x16x32_bf16(afr, cb[kt], acc[h8], 0, 0, 0);
            }
        }
#pragma unroll
        for (int h8 = 0; h8 < 8; ++h8) {
            int h0 = (c * 8 + h8) * 16 + quad * 4;
            f32x4 bv = *(const f32x4*)(b1 + h0);
            short4v o;
#pragma unroll
            for (int i = 0; i < 4; ++i) o[i] = f2bf(acc[h8][i] + bv[i]);
            *(short4v*)(ctxp + (size_t)row * NH + h0) = o;
        }
    }
}

// ---------------------------------------------------------------------------
// Main persistent kernel: each wave owns 16 rows for all 32 steps.
// z, log_w live in registers in the z-B-frag layout:
//   lane l holds elem [row = base+(l&15)][k = kt*32 + (l>>4)*8 + j]
// LDS (64 KB static, per-wave 16 KB slice, XOR-swizzled, no barriers needed):
//   hid[m][512] bf16  (written from GEMM1 C-frags as 8B chunks, read as 16B)
//   u  [m][128] f32   (aliased into same slice; strictly after hid reads)
// ---------------------------------------------------------------------------
__global__ __launch_bounds__(256) void diffusion_main(
    const float* __restrict__ eps0, const float* __restrict__ eps,
    const float* __restrict__ beta, const float* __restrict__ sigma0,
    const float* __restrict__ b2, const float* __restrict__ t_emb,
    const float* __restrict__ target_mu,
    const short* __restrict__ w1aT, const short* __restrict__ w2T,
    const short* __restrict__ ctxp, float* __restrict__ out)
{
    __shared__ alignas(16) char lds[65536];
    const int w = threadIdx.x >> 6;
    const int lane = threadIdx.x & 63;
    const int quad = lane >> 4;
    const int m = lane & 15;
    const int row = (blockIdx.x * 4 + w) * 16 + m;
    char* wb = lds + w * 16384;
    const int sw8 = 2 * (m & 7);   // swizzle for 8B hid granules
    const int sw16 = (m & 7);      // swizzle for 16B u granules
    const float dt = 1.0f / 32.0f;

    const float s0 = sigma0[0];
    const float logs0 = logf(s0);

    float zr[4][8], lw[4][8];
#pragma unroll
    for (int kt = 0; kt < 4; ++kt) {
        f32x4 a = *(const f32x4*)(eps0 + (size_t)row * NZ + kt * 32 + quad * 8);
        f32x4 b = *(const f32x4*)(eps0 + (size_t)row * NZ + kt * 32 + quad * 8 + 4);
#pragma unroll
        for (int j = 0; j < 4; ++j) {
            zr[kt][j] = s0 * a[j]; zr[kt][4 + j] = s0 * b[j];
            lw[kt][j] = 0.f;       lw[kt][4 + j] = 0.f;
        }
    }
    const f32x4 zero = {0.f, 0.f, 0.f, 0.f};

    for (int t = 0; t < NT; ++t) {
        const float bfv = beta[t];
        const float bbv = beta[(t + NT - 1) & (NT - 1)];
        const float sf = sqrtf(2.f * bfv * dt) * s0;
        const float sb = sqrtf(2.f * bbv * dt) * s0;
        const float inv_sb = 1.f / sb;
        const float dlog = logf(sf) - logf(sb);

        // stage this step's noise early (HBM stream)
        float er[4][8];
        const float* ept = eps + (size_t)t * NB * NZ + (size_t)row * NZ;
#pragma unroll
        for (int kt = 0; kt < 4; ++kt) {
            f32x4 a = *(const f32x4*)(ept + kt * 32 + quad * 8);
            f32x4 b = *(const f32x4*)(ept + kt * 32 + quad * 8 + 4);
#pragma unroll
            for (int j = 0; j < 4; ++j) { er[kt][j] = a[j]; er[kt][4 + j] = b[j]; }
        }
        // z -> bf16 B-frags (registers already in frag layout)
        short8 zb[4];
#pragma unroll
        for (int kt = 0; kt < 4; ++kt) {
            short8 v;
#pragma unroll
            for (int j = 0; j < 8; ++j) v[j] = f2bf(zr[kt][j]);
            zb[kt] = v;
        }
        const short* ctrow = ctxp + (size_t)row * NH;
        const float* terow = t_emb + (size_t)t * NHID;

        // GEMM1: hid^T = W1a^T @ z^T, chunked 8 h-tiles to bound acc regs
        for (int c = 0; c < 4; ++c) {
            f32x4 acc[8];
#pragma unroll
            for (int i = 0; i < 8; ++i) acc[i] = zero;
#pragma unroll
            for (int kt = 0; kt < 4; ++kt)
#pragma unroll
                for (int h8 = 0; h8 < 8; ++h8) {
                    int ht = c * 8 + h8;
                    short8 afr = *(const short8*)(w1aT + ((size_t)(ht * 4 + kt) * 64 + lane) * 8);
                    acc[h8] = __builtin_amdgcn_mfma_f32_16x16x32_bf16(afr, zb[kt], acc[h8], 0, 0, 0);
                }
#pragma unroll
            for (int h8 = 0; h8 < 8; ++h8) {
                int ht = c * 8 + h8;
                int h0 = ht * 16 + quad * 4;
                short4v cv = *(const short4v*)(ctrow + h0);
                f32x4 te = *(const f32x4*)(terow + h0);
                short4v o;
#pragma unroll
                for (int i = 0; i < 4; ++i) {
                    float pre = acc[h8][i] + bf2f(cv[i]) + te[i];
                    o[i] = f2bf(fmaxf(pre, 0.f));
                }
                *(short4v*)(wb + m * 1024 + (((ht * 4 + quad) ^ sw8) << 3)) = o;
            }
        }
        // GEMM2: u^T = W2^T @ hid^T
        f32x4 uacc[8];
#pragma unroll
        for (int i = 0; i < 8; ++i) uacc[i] = zero;
        for (int kt = 0; kt < 16; ++kt) {
            short8 hfr = *(const short8*)(wb + m * 1024 + (((kt * 8 + quad * 2) ^ sw8) << 3));
#pragma unroll
            for (int jt = 0; jt < 8; ++jt) {
                short8 afr = *(const short8*)(w2T + ((size_t)(kt * 8 + jt) * 64 + lane) * 8);
                uacc[jt] = __builtin_amdgcn_mfma_f32_16x16x32_bf16(afr, hfr, uacc[jt], 0, 0, 0);
            }
        }
        // u C-frags -> LDS -> z-layout
#pragma unroll
        for (int jt = 0; jt < 8; ++jt)
            *(f32x4*)(wb + m * 512 + (((jt * 4 + quad) ^ sw16) << 4)) = uacc[jt];
#pragma unroll
        for (int kt = 0; kt < 4; ++kt) {
            f32x4 u0 = *(const f32x4*)(wb + m * 512 + (((kt * 8 + quad * 2) ^ sw16) << 4));
            f32x4 u1 = *(const f32x4*)(wb + m * 512 + (((kt * 8 + quad * 2 + 1) ^ sw16) << 4));
            f32x4 c0 = *(const f32x4*)(b2 + kt * 32 + quad * 8);
            f32x4 c1 = *(const f32x4*)(b2 + kt * 32 + quad * 8 + 4);
            float uu[8];
#pragma unroll
            for (int j = 0; j < 4; ++j) { uu[j] = u0[j] + c0[j]; uu[4 + j] = u1[j] + c1[j]; }
#pragma unroll
            for (int j = 0; j < 8; ++j) {
                float z = zr[kt][j], e = er[kt][j];
                float mu_f = z + (bfv * z + uu[j]) * dt;
                float zn = mu_f + sf * e;
                float mu_b = zn - bbv * zn * dt;
                float d = (z - mu_b) * inv_sb;
                // forward logprob uses (z_next-mu_f)/sig_f == e exactly; 0.5*log2pi cancels
                lw[kt][j] += -0.5f * d * d + 0.5f * e * e + dlog;
                zr[kt][j] = zn;
            }
        }
    }

    // terminal + prior correction; (z0/sig0) == eps0 exactly
    float part = 0.f;
#pragma unroll
    for (int kt = 0; kt < 4; ++kt) {
        f32x4 a = *(const f32x4*)(eps0 + (size_t)row * NZ + kt * 32 + quad * 8);
        f32x4 b = *(const f32x4*)(eps0 + (size_t)row * NZ + kt * 32 + quad * 8 + 4);
        f32x4 ta = *(const f32x4*)(target_mu + (size_t)row * NZ + kt * 32 + quad * 8);
        f32x4 tb = *(const f32x4*)(target_mu + (size_t)row * NZ + kt * 32 + quad * 8 + 4);
#pragma unroll
        for (int j = 0; j < 4; ++j) {
            float d0 = zr[kt][j] - ta[j];
            float d1 = zr[kt][4 + j] - tb[j];
            part += lw[kt][j]     - 0.5f * d0 * d0 + 0.5f * a[j] * a[j] + logs0;
            part += lw[kt][4 + j] - 0.5f * d1 * d1 + 0.5f * b[j] * b[j] + logs0;
        }
    }
#pragma unroll
    for (int off = 32; off >= 1; off >>= 1) part += __shfl_xor(part, off, 64);
    if (lane == 0) atomicAdd(out, part * (1.0f / NB));
}

extern "C" void kernel_launch(void* const* d_in, const int* in_sizes, int n_in,
                              void* d_out, int out_size, void* d_ws, size_t ws_size,
                              hipStream_t stream) {
    const float* ctx  = (const float*)d_in[0];
    const float* eps0 = (const float*)d_in[1];
    const float* eps  = (const float*)d_in[2];
    const float* beta = (const float*)d_in[3];
    const float* sig0 = (const float*)d_in[4];
    const float* W1   = (const float*)d_in[5];
    const float* b1   = (const float*)d_in[6];
    const float* W2   = (const float*)d_in[7];
    const float* b2   = (const float*)d_in[8];
    const float* temb = (const float*)d_in[9];
    const float* tmu  = (const float*)d_in[10];
    float* out = (float*)d_out;

    char* ws = (char*)d_ws;
    short* w1aT = (short*)ws;                  // 131072 B
    short* w2T  = (short*)(ws + 131072);       // 131072 B
    short* w1bT = (short*)(ws + 262144);       // 524288 B
    short* ctxp = (short*)(ws + 786432);       // 16 MiB (bf16 ctx_proj)

    hipMemsetAsync(d_out, 0, sizeof(float), stream);
    pack_weights<<<768, 64, 0, stream>>>(W1, W2, w1aT, w2T, w1bT);
    ctxproj_kernel<<<256, 256, 0, stream>>>(ctx, b1, w1bT, ctxp);
    diffusion_main<<<256, 256, 0, stream>>>(eps0, eps, beta, sig0, b2, temb, tmu,
                                            w1aT, w2T, ctxp, out);
}

// Round 2
// 1888.130 us; speedup vs baseline: 1.2299x; 1.2299x over previous
//
#include <hip/hip_runtime.h>
#include <hip/hip_bf16.h>

#define NB 16384
#define NZ 128
#define NH 512
#define NHID 512
#define NT 32

typedef __attribute__((ext_vector_type(8))) short short8;
typedef __attribute__((ext_vector_type(4))) short short4v;
typedef __attribute__((ext_vector_type(4))) float f32x4;

__device__ __forceinline__ short f2bf(float x) {
    union { __hip_bfloat16 h; short s; } u; u.h = __float2bfloat16(x); return u.s;
}
__device__ __forceinline__ float bf2f(short s) {
    union { unsigned int u; float f; } v; v.u = ((unsigned int)(unsigned short)s) << 16; return v.f;
}

// ---------------------------------------------------------------------------
// Prologue: pack W1a^T, W2^T, W1b^T into MFMA A-fragment order (bf16).
// A-frag for 16x16x32: lane l holds A[m=l&15][k=(l>>4)*8+j], j=0..7 (16B/lane).
// w1aT order [ht(32)][kt(4)]; w2T order [kt(16)][jt(8)]; w1bT order [ht(32)][kt(16)]
// ---------------------------------------------------------------------------
__global__ __launch_bounds__(64) void pack_weights(const float* __restrict__ W1,
                                                   const float* __restrict__ W2,
                                                   short* __restrict__ w1aT,
                                                   short* __restrict__ w2T,
                                                   short* __restrict__ w1bT) {
    int f = blockIdx.x;
    int l = threadIdx.x;
    int quad = l >> 4, m = l & 15;
    float v[8];
    short* dst;
    if (f < 128) {                       // W1a^T : A[h][k] = W1[k][h], k<128
        int ht = f >> 2, kt = f & 3;
#pragma unroll
        for (int j = 0; j < 8; ++j)
            v[j] = W1[(size_t)(kt * 32 + quad * 8 + j) * NH + ht * 16 + m];
        dst = w1aT + ((size_t)f * 64 + l) * 8;
    } else if (f < 256) {                // W2^T : A[j][h] = W2[h][j]
        int g = f - 128; int kt = g >> 3, jt = g & 7;
#pragma unroll
        for (int j = 0; j < 8; ++j)
            v[j] = W2[(size_t)(kt * 32 + quad * 8 + j) * NZ + jt * 16 + m];
        dst = w2T + ((size_t)g * 64 + l) * 8;
    } else {                             // W1b^T : A[h][k] = W1[128+k][h]
        int g = f - 256; int ht = g >> 4, kt = g & 15;
#pragma unroll
        for (int j = 0; j < 8; ++j)
            v[j] = W1[(size_t)(128 + kt * 32 + quad * 8 + j) * NH + ht * 16 + m];
        dst = w1bT + ((size_t)g * 64 + l) * 8;
    }
    short8 o;
#pragma unroll
    for (int j = 0; j < 8; ++j) o[j] = f2bf(v[j]);
    *(short8*)dst = o;
}

// ---------------------------------------------------------------------------
// ctx_proj^T = W1b^T @ ctx^T. 1024 blocks x 4 waves; block = 16 rows,
// wave w handles h-chunk c=w (8 h-tiles, 128 MFMA). 4096 waves total.
// ---------------------------------------------------------------------------
__global__ __launch_bounds__(256) void ctxproj_kernel(const float* __restrict__ ctx,
                                                      const float* __restrict__ b1,
                                                      const short* __restrict__ w1bT,
                                                      short* __restrict__ ctxp) {
    int w = threadIdx.x >> 6;
    int lane = threadIdx.x & 63;
    int quad = lane >> 4, m = lane & 15;
    int row = blockIdx.x * 16 + m;

    short8 cb[16];
    const float* crow = ctx + (size_t)row * NH;
#pragma unroll
    for (int kt = 0; kt < 16; ++kt) {
        f32x4 a = *(const f32x4*)(crow + kt * 32 + quad * 8);
        f32x4 b = *(const f32x4*)(crow + kt * 32 + quad * 8 + 4);
        short8 t;
#pragma unroll
        for (int j = 0; j < 4; ++j) { t[j] = f2bf(a[j]); t[4 + j] = f2bf(b[j]); }
        cb[kt] = t;
    }
    const f32x4 zero = {0.f, 0.f, 0.f, 0.f};
    f32x4 acc[8];
#pragma unroll
    for (int i = 0; i < 8; ++i) acc[i] = zero;
    for (int kt = 0; kt < 16; ++kt) {
#pragma unroll
        for (int h8 = 0; h8 < 8; ++h8) {
            int ht = w * 8 + h8;
            short8 afr = *(const short8*)(w1bT + ((size_t)(ht * 16 + kt) * 64 + lane) * 8);
            acc[h8] = __builtin_amdgcn_mfma_f32_16x16x32_bf16(afr, cb[kt], acc[h8], 0, 0, 0);
        }
    }
#pragma unroll
    for (int h8 = 0; h8 < 8; ++h8) {
        int h0 = (w * 8 + h8) * 16 + quad * 4;
        f32x4 bv = *(const f32x4*)(b1 + h0);
        short4v o;
#pragma unroll
        for (int i = 0; i < 4; ++i) o[i] = f2bf(acc[h8][i] + bv[i]);
        *(short4v*)(ctxp + (size_t)row * NH + h0) = o;
    }
}

// ---------------------------------------------------------------------------
// Main kernel: 512 blocks x 256 threads. Block owns 32 rows (2 rowsets of 16).
// All 4 waves hold duplicate z state for the 32 rows (B-frag layout).
// Wave w: GEMM1 h-tiles [8w,8w+8), GEMM2 j-tiles {2w,2w+1}. Each weight
// A-frag load feeds 2 MFMAs (both rowsets) -> L2 weight traffic halved.
// LDS: hid[2][16][512]bf16 (32KB) + u[2][16][128]f32 (16KB). 2 barriers/step.
// ---------------------------------------------------------------------------
__global__ __launch_bounds__(256, 2) void diffusion_main(
    const float* __restrict__ eps0, const float* __restrict__ eps,
    const float* __restrict__ beta, const float* __restrict__ sigma0,
    const float* __restrict__ b2, const float* __restrict__ t_emb,
    const float* __restrict__ target_mu,
    const short* __restrict__ w1aT, const short* __restrict__ w2T,
    const short* __restrict__ ctxp, float* __restrict__ out)
{
    __shared__ alignas(16) char lds[49152];
    const int w = threadIdx.x >> 6;
    const int lane = threadIdx.x & 63;
    const int quad = lane >> 4;
    const int m = lane & 15;
    const int rowbase = blockIdx.x * 32;
    const int row0 = rowbase + m;
    const int row1 = rowbase + 16 + m;
    char* hidb = lds;            // [rs][m][1024B], granule 8B idx (ht*4+quad)^sw8
    char* ub = lds + 32768;      // [rs][m][512B],  granule 16B idx (jt*4+quad)^sw16
    const int sw8 = 2 * (m & 7);
    const int sw16 = (m & 7);
    const float dt = 1.0f / 32.0f;
    const float s0 = sigma0[0];
    const float logs0 = logf(s0);

    // step-invariant per-lane biases in registers
    short4v cbr[2][8];
#pragma unroll
    for (int c = 0; c < 8; ++c) {
        int h0 = (w * 8 + c) * 16 + quad * 4;
        cbr[0][c] = *(const short4v*)(ctxp + (size_t)row0 * NH + h0);
        cbr[1][c] = *(const short4v*)(ctxp + (size_t)row1 * NH + h0);
    }
    f32x4 b2r[2];
    b2r[0] = *(const f32x4*)(b2 + (w * 2 + 0) * 16 + quad * 4);
    b2r[1] = *(const f32x4*)(b2 + (w * 2 + 1) * 16 + quad * 4);

    float zr[2][4][8];
    float part = 0.f;
#pragma unroll
    for (int rs = 0; rs < 2; ++rs) {
        const float* e0p = eps0 + (size_t)(rs ? row1 : row0) * NZ;
#pragma unroll
        for (int kt = 0; kt < 4; ++kt) {
            f32x4 a = *(const f32x4*)(e0p + kt * 32 + quad * 8);
            f32x4 b = *(const f32x4*)(e0p + kt * 32 + quad * 8 + 4);
#pragma unroll
            for (int j = 0; j < 4; ++j) { zr[rs][kt][j] = s0 * a[j]; zr[rs][kt][4 + j] = s0 * b[j]; }
        }
    }
    const f32x4 zero = {0.f, 0.f, 0.f, 0.f};

    for (int t = 0; t < NT; ++t) {
        const float bfv = beta[t];
        const float bbv = beta[(t + NT - 1) & (NT - 1)];
        const float sf = sqrtf(2.f * bfv * dt) * s0;
        const float sb = sqrtf(2.f * bbv * dt) * s0;
        const float inv_sb = 1.f / sb;
        const float dlog = logf(sf) - logf(sb);

        // z -> bf16 B-frags (regs already in frag layout)
        short8 zb[2][4];
#pragma unroll
        for (int rs = 0; rs < 2; ++rs)
#pragma unroll
            for (int kt = 0; kt < 4; ++kt) {
                short8 v;
#pragma unroll
                for (int j = 0; j < 8; ++j) v[j] = f2bf(zr[rs][kt][j]);
                zb[rs][kt] = v;
            }
        const float* terow = t_emb + (size_t)t * NHID;

        // ---- GEMM1: hid^T = W1a^T @ z^T, this wave's 8 h-tiles ----
#pragma unroll
        for (int c = 0; c < 8; ++c) {
            int ht = w * 8 + c;
            f32x4 acc0 = zero, acc1 = zero;
#pragma unroll
            for (int kt = 0; kt < 4; ++kt) {
                short8 afr = *(const short8*)(w1aT + ((size_t)(ht * 4 + kt) * 64 + lane) * 8);
                acc0 = __builtin_amdgcn_mfma_f32_16x16x32_bf16(afr, zb[0][kt], acc0, 0, 0, 0);
                acc1 = __builtin_amdgcn_mfma_f32_16x16x32_bf16(afr, zb[1][kt], acc1, 0, 0, 0);
            }
            int h0 = ht * 16 + quad * 4;
            f32x4 te = *(const f32x4*)(terow + h0);
            short4v o0, o1;
#pragma unroll
            for (int i = 0; i < 4; ++i) {
                float p0 = acc0[i] + bf2f(cbr[0][c][i]) + te[i];
                float p1 = acc1[i] + bf2f(cbr[1][c][i]) + te[i];
                o0[i] = f2bf(fmaxf(p0, 0.f));
                o1[i] = f2bf(fmaxf(p1, 0.f));
            }
            int gr = ((ht * 4 + quad) ^ sw8) << 3;
            *(short4v*)(hidb + m * 1024 + gr) = o0;
            *(short4v*)(hidb + 16384 + m * 1024 + gr) = o1;
        }
        __syncthreads();   // hid complete

        // ---- GEMM2: u^T = W2^T @ hid^T, this wave's 2 j-tiles ----
        f32x4 uacc[2][2];
        uacc[0][0] = zero; uacc[0][1] = zero; uacc[1][0] = zero; uacc[1][1] = zero;
#pragma unroll
        for (int kt = 0; kt < 16; ++kt) {
            int gr = ((kt * 8 + quad * 2) ^ sw8) << 3;
            short8 h0f = *(const short8*)(hidb + m * 1024 + gr);
            short8 h1f = *(const short8*)(hidb + 16384 + m * 1024 + gr);
#pragma unroll
            for (int p = 0; p < 2; ++p) {
                int jt = w * 2 + p;
                short8 afr = *(const short8*)(w2T + ((size_t)(kt * 8 + jt) * 64 + lane) * 8);
                uacc[p][0] = __builtin_amdgcn_mfma_f32_16x16x32_bf16(afr, h0f, uacc[p][0], 0, 0, 0);
                uacc[p][1] = __builtin_amdgcn_mfma_f32_16x16x32_bf16(afr, h1f, uacc[p][1], 0, 0, 0);
            }
        }
        // write u (+b2 folded) to LDS
#pragma unroll
        for (int p = 0; p < 2; ++p) {
            int jt = w * 2 + p;
            int gu = ((jt * 4 + quad) ^ sw16) << 4;
            f32x4 v0, v1;
#pragma unroll
            for (int i = 0; i < 4; ++i) { v0[i] = uacc[p][0][i] + b2r[p][i]; v1[i] = uacc[p][1][i] + b2r[p][i]; }
            *(f32x4*)(ub + m * 512 + gu) = v0;
            *(f32x4*)(ub + 8192 + m * 512 + gu) = v1;
        }
        __syncthreads();   // u complete

        // ---- elementwise update (duplicated across waves; cheap) ----
#pragma unroll
        for (int rs = 0; rs < 2; ++rs) {
            const float* ept = eps + (size_t)t * NB * NZ + (size_t)(rs ? row1 : row0) * NZ;
            char* urs = ub + rs * 8192 + m * 512;
#pragma unroll
            for (int kt = 0; kt < 4; ++kt) {
                f32x4 ea = *(const f32x4*)(ept + kt * 32 + quad * 8);
                f32x4 eb = *(const f32x4*)(ept + kt * 32 + quad * 8 + 4);
                f32x4 u0 = *(const f32x4*)(urs + (((kt * 8 + quad * 2) ^ sw16) << 4));
                f32x4 u1 = *(const f32x4*)(urs + (((kt * 8 + quad * 2 + 1) ^ sw16) << 4));
                float ee[8], uu[8];
#pragma unroll
                for (int j = 0; j < 4; ++j) { ee[j] = ea[j]; ee[4 + j] = eb[j]; uu[j] = u0[j]; uu[4 + j] = u1[j]; }
#pragma unroll
                for (int j = 0; j < 8; ++j) {
                    float z = zr[rs][kt][j], e = ee[j];
                    float mu_f = z + (bfv * z + uu[j]) * dt;
                    float zn = mu_f + sf * e;
                    float mu_b = zn - bbv * zn * dt;
                    float d = (z - mu_b) * inv_sb;
                    part += -0.5f * d * d + 0.5f * e * e + dlog;
                    zr[rs][kt][j] = zn;
                }
            }
        }
    }

    // terminal + prior correction; (z0/sig0) == eps0 exactly
#pragma unroll
    for (int rs = 0; rs < 2; ++rs) {
        const float* e0p = eps0 + (size_t)(rs ? row1 : row0) * NZ;
        const float* tp = target_mu + (size_t)(rs ? row1 : row0) * NZ;
#pragma unroll
        for (int kt = 0; kt < 4; ++kt) {
            f32x4 a = *(const f32x4*)(e0p + kt * 32 + quad * 8);
            f32x4 b = *(const f32x4*)(e0p + kt * 32 + quad * 8 + 4);
            f32x4 ta = *(const f32x4*)(tp + kt * 32 + quad * 8);
            f32x4 tb = *(const f32x4*)(tp + kt * 32 + quad * 8 + 4);
#pragma unroll
            for (int j = 0; j < 4; ++j) {
                float d0 = zr[rs][kt][j] - ta[j];
                float d1 = zr[rs][kt][4 + j] - tb[j];
                part += -0.5f * d0 * d0 + 0.5f * a[j] * a[j] + logs0;
                part += -0.5f * d1 * d1 + 0.5f * b[j] * b[j] + logs0;
            }
        }
    }
#pragma unroll
    for (int off = 32; off >= 1; off >>= 1) part += __shfl_xor(part, off, 64);
    if (w == 0 && lane == 0) atomicAdd(out, part * (1.0f / NB));
}

extern "C" void kernel_launch(void* const* d_in, const int* in_sizes, int n_in,
                              void* d_out, int out_size, void* d_ws, size_t ws_size,
                              hipStream_t stream) {
    const float* ctx  = (const float*)d_in[0];
    const float* eps0 = (const float*)d_in[1];
    const float* eps  = (const float*)d_in[2];
    const float* beta = (const float*)d_in[3];
    const float* sig0 = (const float*)d_in[4];
    const float* W1   = (const float*)d_in[5];
    const float* b1   = (const float*)d_in[6];
    const float* W2   = (const float*)d_in[7];
    const float* b2   = (const float*)d_in[8];
    const float* temb = (const float*)d_in[9];
    const float* tmu  = (const float*)d_in[10];
    float* out = (float*)d_out;

    char* ws = (char*)d_ws;
    short* w1aT = (short*)ws;                  // 131072 B
    short* w2T  = (short*)(ws + 131072);       // 131072 B
    short* w1bT = (short*)(ws + 262144);       // 524288 B
    short* ctxp = (short*)(ws + 786432);       // 16 MiB (bf16 ctx_proj)

    hipMemsetAsync(d_out, 0, sizeof(float), stream);
    pack_weights<<<768, 64, 0, stream>>>(W1, W2, w1aT, w2T, w1bT);
    ctxproj_kernel<<<1024, 256, 0, stream>>>(ctx, b1, w1bT, ctxp);
    diffusion_main<<<512, 256, 0, stream>>>(eps0, eps, beta, sig0, b2, temb, tmu,
                                            w1aT, w2T, ctxp, out);
}

// Round 3
// 897.209 us; speedup vs baseline: 2.5882x; 2.1044x over previous
//
#include <hip/hip_runtime.h>
#include <hip/hip_bf16.h>

#define NB 16384
#define NZ 128
#define NH 512
#define NHID 512
#define NT 32

typedef __attribute__((ext_vector_type(8))) short short8;
typedef __attribute__((ext_vector_type(4))) short short4v;
typedef __attribute__((ext_vector_type(4))) float f32x4;

__device__ __forceinline__ short f2bf(float x) {
    union { __hip_bfloat16 h; short s; } u; u.h = __float2bfloat16(x); return u.s;
}
__device__ __forceinline__ float bf2f(short s) {
    union { unsigned int u; float f; } v; v.u = ((unsigned int)(unsigned short)s) << 16; return v.f;
}

// ---------------------------------------------------------------------------
// Prologue pack:
//  w1aT  bf16 A-frags [ht(32)][kt(4)]   (128 frags x 1KB)
//  w2T8  fp8  A-frags [kt2(16)][jt(8)]  (128 frags x 512B)
//  w1bT  bf16 A-frags [ht(32)][kt(16)]  (512 frags x 1KB)
// A-frag 16x16x32: lane l holds A[m=l&15][k=(l>>4)*8+j], j=0..7.
// ---------------------------------------------------------------------------
__global__ __launch_bounds__(64) void pack_weights(const float* __restrict__ W1,
                                                   const float* __restrict__ W2,
                                                   short* __restrict__ w1aT,
                                                   long* __restrict__ w2T8,
                                                   short* __restrict__ w1bT) {
    int f = blockIdx.x;
    int l = threadIdx.x;
    int quad = l >> 4, m = l & 15;
    if (f < 128) {                       // W1a^T : A[h][k] = W1[k][h], k<128
        int ht = f >> 2, kt = f & 3;
        short8 o;
#pragma unroll
        for (int j = 0; j < 8; ++j)
            o[j] = f2bf(W1[(size_t)(kt * 32 + quad * 8 + j) * NH + ht * 16 + m]);
        *(short8*)(w1aT + ((size_t)f * 64 + l) * 8) = o;
    } else if (f < 256) {                // W2^T fp8 : A[j][k=h] = W2[h][j]
        int g = f - 128; int kt2 = g >> 3, jt = g & 7;
        float v[8];
#pragma unroll
        for (int j = 0; j < 8; ++j)
            v[j] = W2[(size_t)(kt2 * 32 + quad * 8 + j) * NZ + jt * 16 + m];
        int lo = __builtin_amdgcn_cvt_pk_fp8_f32(v[0], v[1], 0, false);
        lo = __builtin_amdgcn_cvt_pk_fp8_f32(v[2], v[3], lo, true);
        int hi = __builtin_amdgcn_cvt_pk_fp8_f32(v[4], v[5], 0, false);
        hi = __builtin_amdgcn_cvt_pk_fp8_f32(v[6], v[7], hi, true);
        long pv = ((long)(unsigned int)hi << 32) | (unsigned int)lo;
        w2T8[(size_t)g * 64 + l] = pv;
    } else {                             // W1b^T : A[h][k] = W1[128+k][h]
        int g = f - 256; int ht = g >> 4, kt = g & 15;
        short8 o;
#pragma unroll
        for (int j = 0; j < 8; ++j)
            o[j] = f2bf(W1[(size_t)(128 + kt * 32 + quad * 8 + j) * NH + ht * 16 + m]);
        *(short8*)(w1bT + ((size_t)g * 64 + l) * 8) = o;
    }
}

// ---------------------------------------------------------------------------
// Main kernel: 256 blocks x 512 threads (8 waves), 1 block/CU, 64 rows/block.
// Wave w: GEMM1 h-tiles [4w,4w+4) (bf16), GEMM2 j-tile jt=w (fp8),
// elementwise owns rowset rs=w>>1, kt-half w&1 (zr f32 = 16 VGPR).
// LDS 64KB: zbuf[4][16][256B] bf16 | hid[4][16][512B] fp8 | ubuf[4][16][256B] bf16
// All granules XOR-swizzled by per-row m to spread banks. 3 barriers/step.
// ---------------------------------------------------------------------------
__global__ __launch_bounds__(512, 2) void diffusion_main(
    const float* __restrict__ eps0, const float* __restrict__ eps,
    const float* __restrict__ beta, const float* __restrict__ sigma0,
    const float* __restrict__ ctx, const float* __restrict__ b1,
    const float* __restrict__ b2, const float* __restrict__ t_emb,
    const float* __restrict__ target_mu,
    const short* __restrict__ w1aT, const short* __restrict__ w1bT,
    const long* __restrict__ w2T8, float* __restrict__ out)
{
    __shared__ alignas(16) char lds[65536];
    char* zbuf = lds;            // 16KB: rs*4096 + m*256 + g*16,  g=(kt*4+quad)^swz
    char* hidb = lds + 16384;    // 32KB: rs*8192 + m*512 + g2*4,  g2=(ht*4+quad)^sw
    char* ubuf = lds + 49152;    // 16KB: rs*4096 + m*256 + g3*8,  g3=(jt*4+quad)^sw
    const int w = threadIdx.x >> 6;
    const int lane = threadIdx.x & 63;
    const int quad = lane >> 4;
    const int m = lane & 15;
    const int sw = 2 * (m & 7);
    const int swz = (m & 7);
    const int rowbase = blockIdx.x * 64;
    const int ers = w >> 1;                  // elementwise rowset
    const int ek0 = 2 * (w & 1);             // elementwise kt base
    const int erow = rowbase + ers * 16 + m;
    const float dt = 1.0f / 32.0f;
    const float s0 = sigma0[0];
    const float logs0 = logf(s0);
    const f32x4 zero = {0.f, 0.f, 0.f, 0.f};

    // ---- prologue: cbr[c][rs] = (ctx @ W1b + b1) for this wave's h-tiles ----
    f32x4 pacc[4][4];
#pragma unroll
    for (int c = 0; c < 4; ++c)
#pragma unroll
        for (int rs = 0; rs < 4; ++rs) pacc[c][rs] = zero;
#pragma unroll 4
    for (int kt = 0; kt < 16; ++kt) {
        short8 cf[4];
#pragma unroll
        for (int rs = 0; rs < 4; ++rs) {
            const float* cp = ctx + (size_t)(rowbase + rs * 16 + m) * NH + kt * 32 + quad * 8;
            f32x4 a = *(const f32x4*)cp;
            f32x4 b = *(const f32x4*)(cp + 4);
            short8 tt;
#pragma unroll
            for (int j = 0; j < 4; ++j) { tt[j] = f2bf(a[j]); tt[4 + j] = f2bf(b[j]); }
            cf[rs] = tt;
        }
#pragma unroll
        for (int c = 0; c < 4; ++c) {
            short8 af = *(const short8*)(w1bT + ((size_t)((w * 4 + c) * 16 + kt) * 64 + lane) * 8);
#pragma unroll
            for (int rs = 0; rs < 4; ++rs)
                pacc[c][rs] = __builtin_amdgcn_mfma_f32_16x16x32_bf16(af, cf[rs], pacc[c][rs], 0, 0, 0);
        }
    }
    short4v cbr[4][4];
#pragma unroll
    for (int c = 0; c < 4; ++c) {
        f32x4 bv = *(const f32x4*)(b1 + (w * 4 + c) * 16 + quad * 4);
#pragma unroll
        for (int rs = 0; rs < 4; ++rs) {
            short4v o;
#pragma unroll
            for (int i = 0; i < 4; ++i) o[i] = f2bf(pacc[c][rs][i] + bv[i]);
            cbr[c][rs] = o;
        }
    }
    f32x4 b2r = *(const f32x4*)(b2 + w * 16 + quad * 4);

    // ---- init own z-state and publish to zbuf ----
    float zr[2][8];
    float part = 0.f;
#pragma unroll
    for (int kk = 0; kk < 2; ++kk) {
        int kt = ek0 + kk;
        const float* ep = eps0 + (size_t)erow * NZ + kt * 32 + quad * 8;
        f32x4 a = *(const f32x4*)ep;
        f32x4 b = *(const f32x4*)(ep + 4);
        short8 zbw;
#pragma unroll
        for (int j = 0; j < 4; ++j) {
            zr[kk][j] = s0 * a[j]; zr[kk][4 + j] = s0 * b[j];
            zbw[j] = f2bf(zr[kk][j]); zbw[4 + j] = f2bf(zr[kk][4 + j]);
        }
        *(short8*)(zbuf + ers * 4096 + m * 256 + (((kt * 4 + quad) ^ swz) << 4)) = zbw;
    }

#pragma unroll 1
    for (int t = 0; t < NT; ++t) {
        const float bfv = beta[t];
        const float bbv = beta[(t + NT - 1) & (NT - 1)];
        const float sf = sqrtf(2.f * bfv * dt) * s0;
        const float inv_sb = __frsqrt_rn(2.f * bbv * dt) / s0;
        const float dlog = 0.5f * (logf(bfv) - logf(bbv));

        // prefetch (global; drained at barrier A which is fine - they're L2 hits)
        short8 wf[4];
        f32x4 te[4];
#pragma unroll
        for (int c = 0; c < 4; ++c) {
            wf[c] = *(const short8*)(w1aT + ((size_t)((w * 4 + c) * 4 + 0) * 64 + lane) * 8);
            te[c] = *(const f32x4*)(t_emb + (size_t)t * NHID + (w * 4 + c) * 16 + quad * 4);
        }
        __syncthreads();   // A: zbuf ready

        // ---- GEMM1 (bf16): hid^T = W1a^T @ z^T for h-tiles [4w,4w+4) ----
        f32x4 g1[4][4];
#pragma unroll
        for (int c = 0; c < 4; ++c)
#pragma unroll
            for (int rs = 0; rs < 4; ++rs) g1[c][rs] = zero;
#pragma unroll
        for (int kt = 0; kt < 4; ++kt) {
            short8 zb[4];
#pragma unroll
            for (int rs = 0; rs < 4; ++rs)
                zb[rs] = *(const short8*)(zbuf + rs * 4096 + m * 256 + (((kt * 4 + quad) ^ swz) << 4));
            short8 cur[4];
#pragma unroll
            for (int c = 0; c < 4; ++c) cur[c] = wf[c];
            if (kt < 3) {
#pragma unroll
                for (int c = 0; c < 4; ++c)
                    wf[c] = *(const short8*)(w1aT + ((size_t)((w * 4 + c) * 4 + kt + 1) * 64 + lane) * 8);
            }
#pragma unroll
            for (int c = 0; c < 4; ++c)
#pragma unroll
                for (int rs = 0; rs < 4; ++rs)
                    g1[c][rs] = __builtin_amdgcn_mfma_f32_16x16x32_bf16(cur[c], zb[rs], g1[c][rs], 0, 0, 0);
        }
        // epilogue: +cbr +te, relu, pack fp8, write hid
#pragma unroll
        for (int c = 0; c < 4; ++c) {
            int g2 = (((w * 4 + c) * 4 + quad) ^ sw) << 2;
#pragma unroll
            for (int rs = 0; rs < 4; ++rs) {
                float p0 = fmaxf(g1[c][rs][0] + bf2f(cbr[c][rs][0]) + te[c][0], 0.f);
                float p1 = fmaxf(g1[c][rs][1] + bf2f(cbr[c][rs][1]) + te[c][1], 0.f);
                float p2 = fmaxf(g1[c][rs][2] + bf2f(cbr[c][rs][2]) + te[c][2], 0.f);
                float p3 = fmaxf(g1[c][rs][3] + bf2f(cbr[c][rs][3]) + te[c][3], 0.f);
                int pk = __builtin_amdgcn_cvt_pk_fp8_f32(p0, p1, 0, false);
                pk = __builtin_amdgcn_cvt_pk_fp8_f32(p2, p3, pk, true);
                *(int*)(hidb + rs * 8192 + m * 512 + g2) = pk;
            }
        }
        __syncthreads();   // B: hid ready

        // eps prefetch for phase E (flies during GEMM2, drained at barrier C)
        f32x4 ef[2][2];
        {
            const float* ept = eps + (size_t)t * NB * NZ + (size_t)erow * NZ;
#pragma unroll
            for (int kk = 0; kk < 2; ++kk) {
                ef[kk][0] = *(const f32x4*)(ept + (ek0 + kk) * 32 + quad * 8);
                ef[kk][1] = *(const f32x4*)(ept + (ek0 + kk) * 32 + quad * 8 + 4);
            }
        }

        // ---- GEMM2 (fp8): u^T = W2^T @ hid^T for j-tile jt=w ----
        f32x4 ua[4];
#pragma unroll
        for (int rs = 0; rs < 4; ++rs) ua[rs] = zero;
#pragma unroll
        for (int kt2 = 0; kt2 < 16; ++kt2) {
            long af = w2T8[(size_t)(kt2 * 8 + w) * 64 + lane];
#pragma unroll
            for (int rs = 0; rs < 4; ++rs) {
                long hf = *(const long*)(hidb + rs * 8192 + m * 512 + (((kt2 * 8 + quad * 2) ^ sw) << 2));
                ua[rs] = __builtin_amdgcn_mfma_f32_16x16x32_fp8_fp8(af, hf, ua[rs], 0, 0, 0);
            }
        }
        // write u (+b2) as bf16
#pragma unroll
        for (int rs = 0; rs < 4; ++rs) {
            short4v o;
#pragma unroll
            for (int i = 0; i < 4; ++i) o[i] = f2bf(ua[rs][i] + b2r[i]);
            *(short4v*)(ubuf + rs * 4096 + m * 256 + (((w * 4 + quad) ^ sw) << 3)) = o;
        }
        __syncthreads();   // C: ubuf ready

        // ---- elementwise: own rowset/kt-half; update zr, part; publish zbuf ----
#pragma unroll
        for (int kk = 0; kk < 2; ++kk) {
            int kt = ek0 + kk;
            short8 uv = *(const short8*)(ubuf + ers * 4096 + m * 256 + (((kt * 8 + quad * 2) ^ sw) << 3));
            float ee[8];
#pragma unroll
            for (int j = 0; j < 4; ++j) { ee[j] = ef[kk][0][j]; ee[4 + j] = ef[kk][1][j]; }
            short8 zbw;
#pragma unroll
            for (int j = 0; j < 8; ++j) {
                float z = zr[kk][j];
                float e = ee[j];
                float uu = bf2f(uv[j]);
                float mu_f = z + (bfv * z + uu) * dt;
                float zn = mu_f + sf * e;
                float d = (z - zn * (1.f - bbv * dt)) * inv_sb;
                part += -0.5f * d * d + 0.5f * e * e + dlog;
                zr[kk][j] = zn;
                zbw[j] = f2bf(zn);
            }
            *(short8*)(zbuf + ers * 4096 + m * 256 + (((kt * 4 + quad) ^ swz) << 4)) = zbw;
        }
    }

    // ---- terminal + prior correction: (z0/s0) == eps0 exactly ----
#pragma unroll
    for (int kk = 0; kk < 2; ++kk) {
        int kt = ek0 + kk;
        const float* ep = eps0 + (size_t)erow * NZ + kt * 32 + quad * 8;
        const float* tp = target_mu + (size_t)erow * NZ + kt * 32 + quad * 8;
        f32x4 a = *(const f32x4*)ep;
        f32x4 b = *(const f32x4*)(ep + 4);
        f32x4 ta = *(const f32x4*)tp;
        f32x4 tb = *(const f32x4*)(tp + 4);
#pragma unroll
        for (int j = 0; j < 4; ++j) {
            float d0 = zr[kk][j] - ta[j];
            float d1 = zr[kk][4 + j] - tb[j];
            part += -0.5f * d0 * d0 + 0.5f * a[j] * a[j] + logs0;
            part += -0.5f * d1 * d1 + 0.5f * b[j] * b[j] + logs0;
        }
    }
#pragma unroll
    for (int off = 32; off >= 1; off >>= 1) part += __shfl_xor(part, off, 64);
    if (lane == 0) atomicAdd(out, part * (1.0f / NB));
}

extern "C" void kernel_launch(void* const* d_in, const int* in_sizes, int n_in,
                              void* d_out, int out_size, void* d_ws, size_t ws_size,
                              hipStream_t stream) {
    const float* ctx  = (const float*)d_in[0];
    const float* eps0 = (const float*)d_in[1];
    const float* eps  = (const float*)d_in[2];
    const float* beta = (const float*)d_in[3];
    const float* sig0 = (const float*)d_in[4];
    const float* W1   = (const float*)d_in[5];
    const float* b1   = (const float*)d_in[6];
    const float* W2   = (const float*)d_in[7];
    const float* b2   = (const float*)d_in[8];
    const float* temb = (const float*)d_in[9];
    const float* tmu  = (const float*)d_in[10];
    float* out = (float*)d_out;

    char* ws = (char*)d_ws;
    short* w1aT = (short*)ws;                  // 131072 B
    long*  w2T8 = (long*)(ws + 131072);        //  65536 B (fp8 frags)
    short* w1bT = (short*)(ws + 196608);       // 524288 B

    hipMemsetAsync(d_out, 0, sizeof(float), stream);
    pack_weights<<<768, 64, 0, stream>>>(W1, W2, w1aT, w2T8, w1bT);
    diffusion_main<<<256, 512, 0, stream>>>(eps0, eps, beta, sig0, ctx, b1, b2,
                                            temb, tmu, w1aT, w1bT, w2T8, out);
}

// Round 4
// 560.867 us; speedup vs baseline: 4.1403x; 1.5997x over previous
//
#include <hip/hip_runtime.h>
#include <hip/hip_bf16.h>

#define NB 16384
#define NZ 128
#define NH 512
#define NHID 512
#define NT 32

typedef __attribute__((ext_vector_type(8))) short short8;
typedef __attribute__((ext_vector_type(4))) short short4v;
typedef __attribute__((ext_vector_type(4))) float f32x4;

__device__ __forceinline__ short f2bf(float x) {
    union { __hip_bfloat16 h; short s; } u; u.h = __float2bfloat16(x); return u.s;
}
__device__ __forceinline__ float bf2f(short s) {
    union { unsigned int u; float f; } v; v.u = ((unsigned int)(unsigned short)s) << 16; return v.f;
}

// ---------------------------------------------------------------------------
// Prologue pack:
//  w1aT  bf16 A-frags [ht(32)][kt(4)]   (128 frags x 1KB)
//  w2T8  fp8  A-frags [kt2(16)][jt(8)]  (128 frags x 512B)
//  w1bT  bf16 A-frags [ht(32)][kt(16)]  (512 frags x 1KB)
// A-frag 16x16x32: lane l holds A[m=l&15][k=(l>>4)*8+j], j=0..7.
// ---------------------------------------------------------------------------
__global__ __launch_bounds__(64) void pack_weights(const float* __restrict__ W1,
                                                   const float* __restrict__ W2,
                                                   short* __restrict__ w1aT,
                                                   long* __restrict__ w2T8,
                                                   short* __restrict__ w1bT) {
    int f = blockIdx.x;
    int l = threadIdx.x;
    int quad = l >> 4, m = l & 15;
    if (f < 128) {                       // W1a^T : A[h][k] = W1[k][h], k<128
        int ht = f >> 2, kt = f & 3;
        short8 o;
#pragma unroll
        for (int j = 0; j < 8; ++j)
            o[j] = f2bf(W1[(size_t)(kt * 32 + quad * 8 + j) * NH + ht * 16 + m]);
        *(short8*)(w1aT + ((size_t)f * 64 + l) * 8) = o;
    } else if (f < 256) {                // W2^T fp8 : A[j][k=h] = W2[h][j]
        int g = f - 128; int kt2 = g >> 3, jt = g & 7;
        float v[8];
#pragma unroll
        for (int j = 0; j < 8; ++j)
            v[j] = W2[(size_t)(kt2 * 32 + quad * 8 + j) * NZ + jt * 16 + m];
        int lo = __builtin_amdgcn_cvt_pk_fp8_f32(v[0], v[1], 0, false);
        lo = __builtin_amdgcn_cvt_pk_fp8_f32(v[2], v[3], lo, true);
        int hi = __builtin_amdgcn_cvt_pk_fp8_f32(v[4], v[5], 0, false);
        hi = __builtin_amdgcn_cvt_pk_fp8_f32(v[6], v[7], hi, true);
        long pv = ((long)(unsigned int)hi << 32) | (unsigned int)lo;
        w2T8[(size_t)g * 64 + l] = pv;
    } else {                             // W1b^T : A[h][k] = W1[128+k][h]
        int g = f - 256; int ht = g >> 4, kt = g & 15;
        short8 o;
#pragma unroll
        for (int j = 0; j < 8; ++j)
            o[j] = f2bf(W1[(size_t)(128 + kt * 32 + quad * 8 + j) * NH + ht * 16 + m]);
        *(short8*)(w1bT + ((size_t)g * 64 + l) * 8) = o;
    }
}

// ---------------------------------------------------------------------------
// Main: 256 blocks x 512 thr (8 waves), 64 rows/block. Weights in REGISTERS
// for all 32 steps (wave w: W1a h-tiles [4w,4w+4) bf16 = 64 VGPR; W2 jt=w
// fp8 = 32 VGPR). T-loop global loads: eps + t_emb only.
// LDS 49KB: zu[4][16][256B] bf16 (z and u, phase-disjoint) | hid[4][16][512B]
// fp8 | sconst[32][8]f32. XOR-swizzled, precomputed bases.
// Barriers: A,B = __syncthreads; C = raw s_barrier + lgkmcnt-only wait so the
// eps prefetch (issued at GEMM2 start) survives into the elementwise phase.
// ---------------------------------------------------------------------------
__global__ __launch_bounds__(512, 2) void diffusion_main(
    const float* __restrict__ eps0, const float* __restrict__ eps,
    const float* __restrict__ beta, const float* __restrict__ sigma0,
    const float* __restrict__ ctx, const float* __restrict__ b1,
    const float* __restrict__ b2, const float* __restrict__ t_emb,
    const float* __restrict__ target_mu,
    const short* __restrict__ w1aT, const short* __restrict__ w1bT,
    const long* __restrict__ w2T8, float* __restrict__ out)
{
    __shared__ alignas(16) char lds[50176];
    char* zu = lds;                      // 16 KB
    char* hidb = lds + 16384;            // 32 KB
    float* scb = (float*)(lds + 49152);  // 1 KB step constants
    const int w = threadIdx.x >> 6;
    const int lane = threadIdx.x & 63;
    const int quad = lane >> 4;
    const int m = lane & 15;
    const int swz = m & 7;
    const int sw = swz << 1;
    const int rowbase = blockIdx.x * 64;
    const int ers = w >> 1;
    const int ek0 = (w & 1) << 1;
    const int erow = rowbase + ers * 16 + m;
    const float dt = 1.0f / 32.0f;
    const float s0 = sigma0[0];
    const float logs0 = logf(s0);
    const f32x4 zero = {0.f, 0.f, 0.f, 0.f};

    // XOR-swizzle address bases (per-lane constants)
    const int zu_base = m * 256 + ((quad ^ swz) << 4);                    // ^ (kt<<6), +rs*4096
    const int hw_base = m * 512 + ((((quad ^ sw)) << 2) ^ (w << 6));      // ^ (c<<4),  +rs*8192
    const int hr_base = m * 512 + (((quad << 1) ^ sw) << 2);              // ^ (kt2<<5),+rs*8192
    const int ubw_off = m * 256 + ((((w << 1) + (quad >> 1)) ^ swz) << 4) + ((quad & 1) << 3);

    // step constants (computed once)
    if (threadIdx.x < 32) {
        int t = threadIdx.x;
        float bfv = beta[t];
        float bbv = beta[(t + 31) & 31];
        float sf = sqrtf(2.f * bfv * dt) * s0;
        float sb = sqrtf(2.f * bbv * dt) * s0;
        scb[t * 8 + 0] = bfv;
        scb[t * 8 + 1] = sf;
        scb[t * 8 + 2] = 1.f / sb;
        scb[t * 8 + 3] = 0.5f * (logf(bfv) - logf(bbv));
        scb[t * 8 + 4] = 1.f - bbv * dt;
    }

    // ---- prologue: cbr[c][rs] = (ctx @ W1b + b1), this wave's 4 h-tiles ----
    f32x4 pacc[4][4];
#pragma unroll
    for (int c = 0; c < 4; ++c)
#pragma unroll
        for (int rs = 0; rs < 4; ++rs) pacc[c][rs] = zero;
#pragma unroll 4
    for (int kt = 0; kt < 16; ++kt) {
        short8 cf[4];
#pragma unroll
        for (int rs = 0; rs < 4; ++rs) {
            const float* cp = ctx + (size_t)(rowbase + rs * 16 + m) * NH + kt * 32 + quad * 8;
            f32x4 a = *(const f32x4*)cp;
            f32x4 b = *(const f32x4*)(cp + 4);
            short8 tt;
#pragma unroll
            for (int j = 0; j < 4; ++j) { tt[j] = f2bf(a[j]); tt[4 + j] = f2bf(b[j]); }
            cf[rs] = tt;
        }
#pragma unroll
        for (int c = 0; c < 4; ++c) {
            short8 af = *(const short8*)(w1bT + ((size_t)((w * 4 + c) * 16 + kt) * 64 + lane) * 8);
#pragma unroll
            for (int rs = 0; rs < 4; ++rs)
                pacc[c][rs] = __builtin_amdgcn_mfma_f32_16x16x32_bf16(af, cf[rs], pacc[c][rs], 0, 0, 0);
        }
    }
    short4v cbr[4][4];
#pragma unroll
    for (int c = 0; c < 4; ++c) {
        f32x4 bv = *(const f32x4*)(b1 + (w * 4 + c) * 16 + quad * 4);
#pragma unroll
        for (int rs = 0; rs < 4; ++rs) {
            short4v o;
#pragma unroll
            for (int i = 0; i < 4; ++i) o[i] = f2bf(pacc[c][rs][i] + bv[i]);
            cbr[c][rs] = o;
        }
    }
    f32x4 b2r = *(const f32x4*)(b2 + w * 16 + quad * 4);

    // ---- persistent weights into registers ----
    short8 wf1[4][4];
#pragma unroll
    for (int c = 0; c < 4; ++c)
#pragma unroll
        for (int kt = 0; kt < 4; ++kt)
            wf1[c][kt] = *(const short8*)(w1aT + ((size_t)((w * 4 + c) * 4 + kt) * 64 + lane) * 8);
    long wf2[16];
#pragma unroll
    for (int kt2 = 0; kt2 < 16; ++kt2)
        wf2[kt2] = w2T8[(size_t)(kt2 * 8 + w) * 64 + lane];

    // ---- init own z slice, publish to zu ----
    float zr[2][8];
    float part = 0.f;
#pragma unroll
    for (int kk = 0; kk < 2; ++kk) {
        int kt = ek0 + kk;
        const float* ep = eps0 + (size_t)erow * NZ + kt * 32 + quad * 8;
        f32x4 a = *(const f32x4*)ep;
        f32x4 b = *(const f32x4*)(ep + 4);
        short8 zbw;
#pragma unroll
        for (int j = 0; j < 4; ++j) {
            zr[kk][j] = s0 * a[j]; zr[kk][4 + j] = s0 * b[j];
            zbw[j] = f2bf(zr[kk][j]); zbw[4 + j] = f2bf(zr[kk][4 + j]);
        }
        *(short8*)(zu + ers * 4096 + (zu_base ^ (kt << 6))) = zbw;
    }
    __syncthreads();   // A (initial)

#pragma unroll 1
    for (int t = 0; t < NT; ++t) {
        // ---- GEMM1 (bf16, weights in regs): 2 chunks of 2 h-tiles ----
#pragma unroll
        for (int cc = 0; cc < 2; ++cc) {
            f32x4 g1[2][4];
#pragma unroll
            for (int c2 = 0; c2 < 2; ++c2)
#pragma unroll
                for (int rs = 0; rs < 4; ++rs) g1[c2][rs] = zero;
#pragma unroll
            for (int kt = 0; kt < 4; ++kt) {
                short8 zb[4];
#pragma unroll
                for (int rs = 0; rs < 4; ++rs)
                    zb[rs] = *(const short8*)(zu + rs * 4096 + (zu_base ^ (kt << 6)));
#pragma unroll
                for (int c2 = 0; c2 < 2; ++c2)
#pragma unroll
                    for (int rs = 0; rs < 4; ++rs)
                        g1[c2][rs] = __builtin_amdgcn_mfma_f32_16x16x32_bf16(
                            wf1[cc * 2 + c2][kt], zb[rs], g1[c2][rs], 0, 0, 0);
            }
#pragma unroll
            for (int c2 = 0; c2 < 2; ++c2) {
                int c = cc * 2 + c2;
                f32x4 te = *(const f32x4*)(t_emb + (size_t)t * NHID + (w * 4 + c) * 16 + quad * 4);
#pragma unroll
                for (int rs = 0; rs < 4; ++rs) {
                    float p0 = fmaxf(g1[c2][rs][0] + bf2f(cbr[c][rs][0]) + te[0], 0.f);
                    float p1 = fmaxf(g1[c2][rs][1] + bf2f(cbr[c][rs][1]) + te[1], 0.f);
                    float p2 = fmaxf(g1[c2][rs][2] + bf2f(cbr[c][rs][2]) + te[2], 0.f);
                    float p3 = fmaxf(g1[c2][rs][3] + bf2f(cbr[c][rs][3]) + te[3], 0.f);
                    int pk = __builtin_amdgcn_cvt_pk_fp8_f32(p0, p1, 0, false);
                    pk = __builtin_amdgcn_cvt_pk_fp8_f32(p2, p3, pk, true);
                    *(int*)(hidb + rs * 8192 + (hw_base ^ (c << 4))) = pk;
                }
            }
        }
        __syncthreads();   // B: hid ready (nothing global in flight)

        // eps prefetch — stays in flight across raw barrier C
        f32x4 ef[2][2];
        {
            const float* ept = eps + (size_t)t * NB * NZ + (size_t)erow * NZ;
#pragma unroll
            for (int kk = 0; kk < 2; ++kk) {
                ef[kk][0] = *(const f32x4*)(ept + (ek0 + kk) * 32 + quad * 8);
                ef[kk][1] = *(const f32x4*)(ept + (ek0 + kk) * 32 + quad * 8 + 4);
            }
        }

        // ---- GEMM2 (fp8, weights in regs): j-tile jt=w ----
        f32x4 ua[4];
#pragma unroll
        for (int rs = 0; rs < 4; ++rs) ua[rs] = zero;
#pragma unroll
        for (int kt2 = 0; kt2 < 16; ++kt2) {
            long wfr = wf2[kt2];
#pragma unroll
            for (int rs = 0; rs < 4; ++rs) {
                long hf = *(const long*)(hidb + rs * 8192 + (hr_base ^ (kt2 << 5)));
                ua[rs] = __builtin_amdgcn_mfma_f32_16x16x32_fp8_fp8(wfr, hf, ua[rs], 0, 0, 0);
            }
        }
        // u (+b2) into zu region (z no longer needed there; lives in zr regs)
#pragma unroll
        for (int rs = 0; rs < 4; ++rs) {
            short4v o;
#pragma unroll
            for (int i = 0; i < 4; ++i) o[i] = f2bf(ua[rs][i] + b2r[i]);
            *(short4v*)(zu + rs * 4096 + ubw_off) = o;
        }
        __builtin_amdgcn_s_waitcnt(0xC07F);   // lgkmcnt(0) only — eps stays in flight
        __builtin_amdgcn_s_barrier();          // C: u ready

        // ---- elementwise: own rowset + kt-half ----
        f32x4 sca = *(const f32x4*)(scb + t * 8);
        float c1mb = scb[t * 8 + 4];
#pragma unroll
        for (int kk = 0; kk < 2; ++kk) {
            int kt = ek0 + kk;
            char* gaddr = zu + ers * 4096 + (zu_base ^ (kt << 6));
            short8 uv = *(const short8*)gaddr;
            float ee[8];
#pragma unroll
            for (int j = 0; j < 4; ++j) { ee[j] = ef[kk][0][j]; ee[4 + j] = ef[kk][1][j]; }
            short8 zbw;
#pragma unroll
            for (int j = 0; j < 8; ++j) {
                float z = zr[kk][j];
                float e = ee[j];
                float uu = bf2f(uv[j]);
                float mu_f = z + (sca[0] * z + uu) * dt;
                float zn = mu_f + sca[1] * e;
                float d = (z - zn * c1mb) * sca[2];
                part += -0.5f * d * d + 0.5f * e * e + sca[3];
                zr[kk][j] = zn;
                zbw[j] = f2bf(zn);
            }
            *(short8*)gaddr = zbw;
        }
        __syncthreads();   // A: z published for next step
    }

    // ---- terminal + prior correction: (z0/s0) == eps0 exactly ----
#pragma unroll
    for (int kk = 0; kk < 2; ++kk) {
        int kt = ek0 + kk;
        const float* ep = eps0 + (size_t)erow * NZ + kt * 32 + quad * 8;
        const float* tp = target_mu + (size_t)erow * NZ + kt * 32 + quad * 8;
        f32x4 a = *(const f32x4*)ep;
        f32x4 b = *(const f32x4*)(ep + 4);
        f32x4 ta = *(const f32x4*)tp;
        f32x4 tb = *(const f32x4*)(tp + 4);
#pragma unroll
        for (int j = 0; j < 4; ++j) {
            float d0 = zr[kk][j] - ta[j];
            float d1 = zr[kk][4 + j] - tb[j];
            part += -0.5f * d0 * d0 + 0.5f * a[j] * a[j] + logs0;
            part += -0.5f * d1 * d1 + 0.5f * b[j] * b[j] + logs0;
        }
    }
#pragma unroll
    for (int off = 32; off >= 1; off >>= 1) part += __shfl_xor(part, off, 64);
    if (lane == 0) atomicAdd(out, part * (1.0f / NB));
}

extern "C" void kernel_launch(void* const* d_in, const int* in_sizes, int n_in,
                              void* d_out, int out_size, void* d_ws, size_t ws_size,
                              hipStream_t stream) {
    const float* ctx  = (const float*)d_in[0];
    const float* eps0 = (const float*)d_in[1];
    const float* eps  = (const float*)d_in[2];
    const float* beta = (const float*)d_in[3];
    const float* sig0 = (const float*)d_in[4];
    const float* W1   = (const float*)d_in[5];
    const float* b1   = (const float*)d_in[6];
    const float* W2   = (const float*)d_in[7];
    const float* b2   = (const float*)d_in[8];
    const float* temb = (const float*)d_in[9];
    const float* tmu  = (const float*)d_in[10];
    float* out = (float*)d_out;

    char* ws = (char*)d_ws;
    short* w1aT = (short*)ws;                  // 131072 B
    long*  w2T8 = (long*)(ws + 131072);        //  65536 B (fp8 frags)
    short* w1bT = (short*)(ws + 196608);       // 524288 B

    hipMemsetAsync(d_out, 0, sizeof(float), stream);
    pack_weights<<<768, 64, 0, stream>>>(W1, W2, w1aT, w2T8, w1bT);
    diffusion_main<<<256, 512, 0, stream>>>(eps0, eps, beta, sig0, ctx, b1, b2,
                                            temb, tmu, w1aT, w1bT, w2T8, out);
}